// Round 13
// baseline (360.899 us; speedup 1.0000x reference)
//
#include <hip/hip_runtime.h>

#define NN 4096
#define SLOPE 0.2f

typedef float f4_t __attribute__((ext_vector_type(4)));
typedef __bf16 bf8v __attribute__((ext_vector_type(8)));
typedef float f32x16 __attribute__((ext_vector_type(16)));

// ---- workspace layout (float offsets unless noted) ----
#define V_OFF     0                        // v1i,v2i,v1s,v2s : 4*128
#define C_OFF     512                      // 4 score constants
#define BT_OFF    516                      // b_total[128]
#define S_OFF     1024                     // s1i,s2i,s1s,s2s : 4*4096
#define HXI_OFF   32768                    // Ld@x kz0 [4096,128]; later REUSED as O_irr kz1
#define HXS_OFF   (HXI_OFF + NN*128)       // Lu@x kz0; later O_sol kz1
#define UI_OFF    (HXS_OFF + NN*128)       // U_irr bf16 hi/lo fragment buffers
#define US_OFF    (UI_OFF + NN*128)        // U_sol bf16 hi/lo fragment buffers
#define XWH_OFF   (US_OFF + NN*128)        // xwhT hi/lo bf16 fragment buffers
#define OI_OFF    (XWH_OFF + NN*128)       // O_irr kz0
#define OS_OFF    (OI_OFF + NN*128)        // O_sol kz0
#define ZP_OFF    (OS_OFF + NN*128)        // P@xWh split-K partials: 8 * [4096,128]
#define WS_FLOATS (ZP_OFF + 8*NN*128)
// tail (bytes): x frags (2MB) | Hx kz1 partials (4MB) | denominators (64KB)
#define XF_BYTE_OFF  ((size_t)WS_FLOATS * 4)
#define HX2_BYTE_OFF (XF_BYTE_OFF + (size_t)2*1024*1024)
#define DEN_BYTE_OFF (HX2_BYTE_OFF + (size_t)4*1024*1024)

// Pad map for fp32 LDS GEMM tiles (4-way -> 2-way, free per m136).
#define XI(c)   ((c) + (((c) >> 5) << 2))   // [0,128) -> [0,140)

// MFMA-fragment layout (B operand, 32x32x16 bf16; verified r5-r12):
#define FRAG(c, k) ((size_t)((k) >> 4) * 2048 + (size_t)((c) >> 5) * 512 \
                    + (size_t)((((c) & 31) + 32 * (((k) >> 3) & 1)) * 8 + ((k) & 7)))

// bf16 round-to-nearest-even helpers
__device__ __forceinline__ unsigned short f2bf(float x) {
  unsigned u = __float_as_uint(x);
  return (unsigned short)((u + 0x7FFFu + ((u >> 16) & 1u)) >> 16);
}
__device__ __forceinline__ float bf2f(unsigned short h) {
  return __uint_as_float(((unsigned)h) << 16);
}
union BFU { unsigned short u[8]; bf8v v; };

// ---------------------------------------------------------------------------
// Prep: v-vectors so s1[i] = x[i,:]·v + c, b_total.
__global__ __launch_bounds__(128) void k_prep(
    const float* __restrict__ Wi_w, const float* __restrict__ Wi_b,
    const float* __restrict__ Ws_w, const float* __restrict__ Ws_b,
    const float* __restrict__ Wh_b, const float* __restrict__ att_irr,
    const float* __restrict__ att_sol, float* __restrict__ ws) {
  const int t = threadIdx.x;
  float v1i = 0.f, v2i = 0.f, v1s = 0.f, v2s = 0.f;
  for (int j = 0; j < 2; ++j) {
    for (int o = 0; o < 128; ++o) {
      const float wi = Wi_w[j*16384 + t*128 + o];
      const float wv = Ws_w[j*16384 + t*128 + o];
      v1i += wi * att_irr[j*128 + o];
      v2i += wi * att_irr[256 + j*128 + o];
      v1s += wv * att_sol[j*128 + o];
      v2s += wv * att_sol[256 + j*128 + o];
    }
  }
  ws[V_OFF + t]       = v1i;
  ws[V_OFF + 128 + t] = v2i;
  ws[V_OFF + 256 + t] = v1s;
  ws[V_OFF + 384 + t] = v2s;
  ws[BT_OFF + t] = Wi_b[t] + Wi_b[128 + t] + Ws_b[t] + Ws_b[128 + t] + Wh_b[t];
  if (t < 4) {
    const float* bb = (t < 2) ? Wi_b : Ws_b;
    const float* aa = ((t < 2) ? att_irr : att_sol) + ((t & 1) ? 256 : 0);
    float c = 0.f;
    for (int k = 0; k < 256; ++k) c += bb[k] * aa[k];
    ws[C_OFF + t] = c;
  }
}

// ---------------------------------------------------------------------------
// Fused pre-pass: blocks 0..127 compute xWh = x@Wh -> bf16 hi/lo fragments;
// blocks 128..1151: scores + x -> bf16 hi/lo fragments (feeds k_hxmm).
__global__ __launch_bounds__(256) void k_pre2(
    const float* __restrict__ x, const float* __restrict__ Wh_w,
    float* __restrict__ ws, unsigned short* __restrict__ xth,
    unsigned short* __restrict__ xtl, unsigned short* __restrict__ xfh,
    unsigned short* __restrict__ xfl) {
  __shared__ __align__(16) float At[32][33];
  __shared__ __align__(16) float Wt[32][144];
  const int t = threadIdx.x;

  if (blockIdx.x < 128) {
    const int rb = blockIdx.x;
    const int rg = t >> 4, cg = t & 15;
    const int r0 = rb * 32;
    float acc[2][8];
    #pragma unroll
    for (int i = 0; i < 2; ++i)
      #pragma unroll
      for (int j = 0; j < 8; ++j) acc[i][j] = 0.f;
    for (int k0 = 0; k0 < 128; k0 += 32) {
      __syncthreads();
      {
        const int row = t >> 3, kq = t & 7;
        const float4 av = *(const float4*)&x[(r0 + row)*128 + k0 + kq*4];
        At[row][kq*4+0] = av.x; At[row][kq*4+1] = av.y;
        At[row][kq*4+2] = av.z; At[row][kq*4+3] = av.w;
      }
      #pragma unroll
      for (int l = 0; l < 4; ++l) {
        const int idx = t + l*256;
        const int kr = idx >> 5, c4 = idx & 31;
        const float4 wv = *(const float4*)&Wh_w[(k0 + kr)*128 + c4*4];
        *(float4*)&Wt[kr][XI(c4*4)] = wv;
      }
      __syncthreads();
      #pragma unroll
      for (int k = 0; k < 32; ++k) {
        const float a0 = At[rg*2 + 0][k];
        const float a1 = At[rg*2 + 1][k];
        const float4 b0 = *(const float4*)&Wt[k][XI(cg*8)];
        const float4 b1 = *(const float4*)&Wt[k][XI(cg*8 + 4)];
        acc[0][0] += a0*b0.x; acc[0][1] += a0*b0.y; acc[0][2] += a0*b0.z; acc[0][3] += a0*b0.w;
        acc[0][4] += a0*b1.x; acc[0][5] += a0*b1.y; acc[0][6] += a0*b1.z; acc[0][7] += a0*b1.w;
        acc[1][0] += a1*b0.x; acc[1][1] += a1*b0.y; acc[1][2] += a1*b0.z; acc[1][3] += a1*b0.w;
        acc[1][4] += a1*b1.x; acc[1][5] += a1*b1.y; acc[1][6] += a1*b1.z; acc[1][7] += a1*b1.w;
      }
    }
    #pragma unroll
    for (int i = 0; i < 2; ++i) {
      const int r = r0 + rg*2 + i;       // r = k-index of pgemm
      #pragma unroll
      for (int j = 0; j < 8; ++j) {
        const int c = cg*8 + j;
        const float val = acc[i][j];
        const unsigned short h = f2bf(val);
        const unsigned short l = f2bf(val - bf2f(h));
        const size_t fa = FRAG(c, r);
        xth[fa] = h;
        xtl[fa] = l;
      }
    }
  } else {
    const int wave = t >> 6, lane = t & 63;
    const int row = (blockIdx.x - 128) * 4 + wave;
    const float* v = ws + V_OFF;
    const float x0 = x[row*128 + lane];
    const float x1 = x[row*128 + 64 + lane];
    {
      const unsigned short h0 = f2bf(x0);
      const unsigned short l0 = f2bf(x0 - bf2f(h0));
      const size_t fa0 = FRAG(lane, row);
      xfh[fa0] = h0; xfl[fa0] = l0;
      const unsigned short h1 = f2bf(x1);
      const unsigned short l1 = f2bf(x1 - bf2f(h1));
      const size_t fa1 = FRAG(lane + 64, row);
      xfh[fa1] = h1; xfl[fa1] = l1;
    }
    float p0 = x0 * v[lane]       + x1 * v[64 + lane];
    float p1 = x0 * v[128 + lane] + x1 * v[192 + lane];
    float p2 = x0 * v[256 + lane] + x1 * v[320 + lane];
    float p3 = x0 * v[384 + lane] + x1 * v[448 + lane];
    #pragma unroll
    for (int off = 32; off; off >>= 1) {
      p0 += __shfl_down(p0, off);
      p1 += __shfl_down(p1, off);
      p2 += __shfl_down(p2, off);
      p3 += __shfl_down(p3, off);
    }
    if (lane == 0) {
      ws[S_OFF + row]          = p0 + ws[C_OFF + 0];
      ws[S_OFF + NN + row]     = p1 + ws[C_OFF + 1];
      ws[S_OFF + 2*NN + row]   = p2 + ws[C_OFF + 2];
      ws[S_OFF + 3*NN + row]   = p3 + ws[C_OFF + 3];
    }
  }
}

// ---------------------------------------------------------------------------
// Dense Hx = L@x via MFMA, v6: register-double-buffered B-FRAGMENTS (the r12
// serial L2 chain) + LDS-staged shared A-fragments + no atomics. Manual
// 2-tile loop body, all register indices compile-time.
__global__ __launch_bounds__(512) void k_hxmm(
    const float* __restrict__ Ld, const float* __restrict__ Lu,
    const unsigned short* __restrict__ xfh, const unsigned short* __restrict__ xfl,
    float* __restrict__ ws, float* __restrict__ hx2) {
  const int bid = blockIdx.x;
  const int br  = (bid >> 2) & 1;
  const int rest = ((bid >> 3) << 2) | (bid & 3);
  const int rblk = rest & 127;
  const int kz   = rest >> 7;
  const int t = threadIdx.x;
  const int lane = t & 63;
  const int n = (t >> 6) & 3, par = t >> 8;
  const int r0 = rblk * 32;
  const int kbase = kz * 2048;
  const float* __restrict__ L = br ? Lu : Ld;
  float* __restrict__ out = kz ? (hx2 + (size_t)br * NN * 128)
                               : (ws + (br ? HXS_OFF : HXI_OFF));

  __shared__ __align__(16) char ahb[2][8192];
  __shared__ __align__(16) char alb[2][8192];

  f32x16 acc;
  #pragma unroll
  for (int e = 0; e < 16; ++e) acc[e] = 0.f;

  // stage mapping: thread covers (row = t>>4, k = kg..kg+7), one 16B slot
  const int srow = t >> 4;
  const int kg   = (t & 15) * 8;
  const int sS   = kg >> 4;
  const int lt   = srow + 32 * ((kg >> 3) & 1);
  const int soff = (sS * 64 + (lt ^ sS)) * 16;
  const float* __restrict__ lrow = L + (size_t)(r0 + srow) * NN + kbase + kg;

  // per-wave B base: tile tt, step si -> + (tt*8 + si)*2048 elements
  const unsigned short* __restrict__ bh_w =
      xfh + ((size_t)(kbase >> 4) + par * 4) * 2048 + n * 512 + lane * 8;
  const unsigned short* __restrict__ bl_w =
      xfl + ((size_t)(kbase >> 4) + par * 4) * 2048 + n * 512 + lane * 8;

  bf8v bhA[4], blA[4], bhB[4], blB[4];

  // prologue: L tile 0 + B tile 0, convert tile 0 -> buf0
  f4_t va = *(const f4_t*)lrow;
  f4_t vb = *(const f4_t*)(lrow + 4);
  #pragma unroll
  for (int si = 0; si < 4; ++si) {
    bhA[si] = *(const bf8v*)(bh_w + (size_t)si * 2048);
    blA[si] = *(const bf8v*)(bl_w + (size_t)si * 2048);
  }
  {
    BFU ph, pl;
    #pragma unroll
    for (int c = 0; c < 8; ++c) {
      const float f = (c < 4) ? va[c] : vb[c - 4];
      const unsigned short hh = f2bf(f);
      ph.u[c] = hh;
      pl.u[c] = f2bf(f - bf2f(hh));
    }
    *(bf8v*)(ahb[0] + soff) = ph.v;
    *(bf8v*)(alb[0] + soff) = pl.v;
  }

  for (int m = 0; m < 8; ++m) {
    const int t1 = 2 * m + 1;
    // issue loads for tile t1 (L + B) ahead of the barrier
    f4_t na = *(const f4_t*)(lrow + t1 * 128);
    f4_t nb = *(const f4_t*)(lrow + t1 * 128 + 4);
    #pragma unroll
    for (int si = 0; si < 4; ++si) {
      bhB[si] = *(const bf8v*)(bh_w + ((size_t)t1 * 8 + si) * 2048);
      blB[si] = *(const bf8v*)(bl_w + ((size_t)t1 * 8 + si) * 2048);
    }
    __syncthreads();
    // compute tile 2m from buf0, B-set A (all regs already resident)
    #pragma unroll
    for (int si = 0; si < 4; ++si) {
      const int s = par * 4 + si;
      const int ra16 = (s * 64 + (lane ^ s)) * 16;
      const bf8v ah = *(const bf8v*)(ahb[0] + ra16);
      const bf8v al = *(const bf8v*)(alb[0] + ra16);
      acc = __builtin_amdgcn_mfma_f32_32x32x16_bf16(ah, bhA[si], acc, 0, 0, 0);
      acc = __builtin_amdgcn_mfma_f32_32x32x16_bf16(al, bhA[si], acc, 0, 0, 0);
      acc = __builtin_amdgcn_mfma_f32_32x32x16_bf16(ah, blA[si], acc, 0, 0, 0);
    }
    // convert tile t1 -> buf1
    {
      BFU ph, pl;
      #pragma unroll
      for (int c = 0; c < 8; ++c) {
        const float f = (c < 4) ? na[c] : nb[c - 4];
        const unsigned short hh = f2bf(f);
        ph.u[c] = hh;
        pl.u[c] = f2bf(f - bf2f(hh));
      }
      *(bf8v*)(ahb[1] + soff) = ph.v;
      *(bf8v*)(alb[1] + soff) = pl.v;
    }
    // issue loads for tile 2m+2
    if (m < 7) {
      va = *(const f4_t*)(lrow + (t1 + 1) * 128);
      vb = *(const f4_t*)(lrow + (t1 + 1) * 128 + 4);
      #pragma unroll
      for (int si = 0; si < 4; ++si) {
        bhA[si] = *(const bf8v*)(bh_w + ((size_t)(t1 + 1) * 8 + si) * 2048);
        blA[si] = *(const bf8v*)(bl_w + ((size_t)(t1 + 1) * 8 + si) * 2048);
      }
    }
    __syncthreads();
    // compute tile t1 from buf1, B-set B
    #pragma unroll
    for (int si = 0; si < 4; ++si) {
      const int s = par * 4 + si;
      const int ra16 = (s * 64 + (lane ^ s)) * 16;
      const bf8v ah = *(const bf8v*)(ahb[1] + ra16);
      const bf8v al = *(const bf8v*)(alb[1] + ra16);
      acc = __builtin_amdgcn_mfma_f32_32x32x16_bf16(ah, bhB[si], acc, 0, 0, 0);
      acc = __builtin_amdgcn_mfma_f32_32x32x16_bf16(al, bhB[si], acc, 0, 0, 0);
      acc = __builtin_amdgcn_mfma_f32_32x32x16_bf16(ah, blB[si], acc, 0, 0, 0);
    }
    // convert tile 2m+2 -> buf0
    if (m < 7) {
      BFU ph, pl;
      #pragma unroll
      for (int c = 0; c < 8; ++c) {
        const float f = (c < 4) ? va[c] : vb[c - 4];
        const unsigned short hh = f2bf(f);
        ph.u[c] = hh;
        pl.u[c] = f2bf(f - bf2f(hh));
      }
      *(bf8v*)(ahb[0] + soff) = ph.v;
      *(bf8v*)(alb[0] + soff) = pl.v;
    }
  }

  // parity reduction via LDS (reuse ahb: 16 KB = red[4][32][32])
  float* red = (float*)&ahb[0][0];
  __syncthreads();
  const int la = lane & 31;
  if (par == 1) {
    #pragma unroll
    for (int reg = 0; reg < 16; ++reg) {
      const int row = (reg & 3) + 8*(reg >> 2) + 4*(lane >> 5);
      red[n*1024 + row*32 + la] = acc[reg];
    }
  }
  __syncthreads();
  if (par == 0) {
    #pragma unroll
    for (int reg = 0; reg < 16; ++reg) {
      const int row = (reg & 3) + 8*(reg >> 2) + 4*(lane >> 5);
      out[(size_t)(r0 + row) * 128 + n*32 + la] = acc[reg] + red[n*1024 + row*32 + la];
    }
  }
}

// ---------------------------------------------------------------------------
// U-GEMMs: U = x@W0 + (Hx_kz0 + Hx_kz1)@W1, emitted as bf16 hi/lo FRAGMENTS.
__global__ __launch_bounds__(256) void k_ugemm(
    const float* __restrict__ x, const float* __restrict__ Wi_w,
    const float* __restrict__ Ws_w, float* __restrict__ ws,
    const float* __restrict__ hx2,
    unsigned short* __restrict__ uih, unsigned short* __restrict__ uil,
    unsigned short* __restrict__ ush, unsigned short* __restrict__ usl) {
  const int rb = blockIdx.x;
  const int sel = blockIdx.y;
  const float* A[2]; const float* A2[2]; const float* W[2];
  unsigned short* uh; unsigned short* ul;
  if (sel == 0) { A[0]=x; A2[0]=nullptr; W[0]=Wi_w;
                  A[1]=ws+HXI_OFF; A2[1]=hx2; W[1]=Wi_w+16384; uh=uih; ul=uil; }
  else          { A[0]=x; A2[0]=nullptr; W[0]=Ws_w;
                  A[1]=ws+HXS_OFF; A2[1]=hx2+(size_t)NN*128; W[1]=Ws_w+16384; uh=ush; ul=usl; }

  __shared__ __align__(16) float At[32][33];
  __shared__ __align__(16) float Wt[32][144];
  const int t = threadIdx.x;
  const int rg = t >> 4, cg = t & 15;
  const int r0 = rb * 32;
  float acc[2][8];
  #pragma unroll
  for (int i = 0; i < 2; ++i)
    #pragma unroll
    for (int j = 0; j < 8; ++j) acc[i][j] = 0.f;

  for (int ps = 0; ps < 2; ++ps) {
    const float* __restrict__ Ap = A[ps];
    const float* __restrict__ Ap2 = A2[ps];
    const float* __restrict__ Wp = W[ps];
    for (int k0 = 0; k0 < 128; k0 += 32) {
      __syncthreads();
      {
        const int row = t >> 3, kq = t & 7;
        float4 av = *(const float4*)&Ap[(r0 + row)*128 + k0 + kq*4];
        if (Ap2) {
          const float4 av2 = *(const float4*)&Ap2[(r0 + row)*128 + k0 + kq*4];
          av.x += av2.x; av.y += av2.y; av.z += av2.z; av.w += av2.w;
        }
        At[row][kq*4+0] = av.x; At[row][kq*4+1] = av.y;
        At[row][kq*4+2] = av.z; At[row][kq*4+3] = av.w;
      }
      #pragma unroll
      for (int l = 0; l < 4; ++l) {
        const int idx = t + l*256;
        const int kr = idx >> 5, c4 = idx & 31;
        const float4 wv = *(const float4*)&Wp[(k0 + kr)*128 + c4*4];
        *(float4*)&Wt[kr][XI(c4*4)] = wv;
      }
      __syncthreads();
      #pragma unroll
      for (int k = 0; k < 32; ++k) {
        const float a0 = At[rg*2 + 0][k];
        const float a1 = At[rg*2 + 1][k];
        const float4 b0 = *(const float4*)&Wt[k][XI(cg*8)];
        const float4 b1 = *(const float4*)&Wt[k][XI(cg*8 + 4)];
        acc[0][0] += a0*b0.x; acc[0][1] += a0*b0.y; acc[0][2] += a0*b0.z; acc[0][3] += a0*b0.w;
        acc[0][4] += a0*b1.x; acc[0][5] += a0*b1.y; acc[0][6] += a0*b1.z; acc[0][7] += a0*b1.w;
        acc[1][0] += a1*b0.x; acc[1][1] += a1*b0.y; acc[1][2] += a1*b0.z; acc[1][3] += a1*b0.w;
        acc[1][4] += a1*b1.x; acc[1][5] += a1*b1.y; acc[1][6] += a1*b1.z; acc[1][7] += a1*b1.w;
      }
    }
  }
  #pragma unroll
  for (int i = 0; i < 2; ++i) {
    const int r = r0 + rg*2 + i;
    #pragma unroll
    for (int j = 0; j < 8; ++j) {
      const int c = cg*8 + j;
      const float val = acc[i][j];
      const unsigned short h = f2bf(val);
      const unsigned short l = f2bf(val - bf2f(h));
      const size_t fa = FRAG(c, r);
      uh[fa] = h;
      ul[fa] = l;
    }
  }
}

// ---------------------------------------------------------------------------
// Dense masked-softmax attention via MFMA, v6: same B-register double-buffer
// as k_hxmm; E computed once/element during stage; per-row denominator LDS.
__global__ __launch_bounds__(512) void k_attnmm(
    const float* __restrict__ Ld, const float* __restrict__ Lu,
    float* __restrict__ ws, const unsigned short* __restrict__ uih,
    const unsigned short* __restrict__ uil, const unsigned short* __restrict__ ush,
    const unsigned short* __restrict__ usl, float* __restrict__ denp) {
  const int bid = blockIdx.x;
  const int br  = (bid >> 2) & 1;
  const int rest = ((bid >> 3) << 2) | (bid & 3);
  const int rblk = rest & 127;
  const int kz   = rest >> 7;
  const int t = threadIdx.x;
  const int lane = t & 63;
  const int n = (t >> 6) & 3, par = t >> 8;
  const int r0 = rblk * 32;
  const int kbase = kz * 2048;
  const float* __restrict__ L = br ? Lu : Ld;
  const unsigned short* __restrict__ ufh = br ? ush : uih;
  const unsigned short* __restrict__ ufl = br ? usl : uil;
  float* __restrict__ out = kz ? (ws + (br ? HXS_OFF : HXI_OFF))
                               : (ws + (br ? OS_OFF : OI_OFF));
  float* __restrict__ dout = denp + (size_t)(kz * 2 + br) * NN;
  const float* __restrict__ s1b = ws + S_OFF + (br ? 2*NN : 0) + r0;
  const float* __restrict__ s2b = ws + S_OFF + (br ? 3*NN : NN) + kbase;

  __shared__ __align__(16) char ahb[2][8192];
  __shared__ __align__(16) char alb[2][8192];
  __shared__ float dend[32][16];

  f32x16 acc;
  #pragma unroll
  for (int e = 0; e < 16; ++e) acc[e] = 0.f;
  float dp = 0.f;

  const int srow = t >> 4;
  const int kg   = (t & 15) * 8;
  const int sS   = kg >> 4;
  const int lt   = srow + 32 * ((kg >> 3) & 1);
  const int soff = (sS * 64 + (lt ^ sS)) * 16;
  const float s1v = s1b[srow];
  const float* __restrict__ lrow = L + (size_t)(r0 + srow) * NN + kbase + kg;
  const float* __restrict__ s2r  = s2b + kg;

  const unsigned short* __restrict__ bh_w =
      ufh + ((size_t)(kbase >> 4) + par * 4) * 2048 + n * 512 + lane * 8;
  const unsigned short* __restrict__ bl_w =
      ufl + ((size_t)(kbase >> 4) + par * 4) * 2048 + n * 512 + lane * 8;

  bf8v bhA[4], blA[4], bhB[4], blB[4];

  // prologue: tile 0
  f4_t va = *(const f4_t*)lrow;
  f4_t vb = *(const f4_t*)(lrow + 4);
  f4_t sa = *(const f4_t*)s2r;
  f4_t sb = *(const f4_t*)(s2r + 4);
  #pragma unroll
  for (int si = 0; si < 4; ++si) {
    bhA[si] = *(const bf8v*)(bh_w + (size_t)si * 2048);
    blA[si] = *(const bf8v*)(bl_w + (size_t)si * 2048);
  }
  {
    BFU ph, pl;
    #pragma unroll
    for (int c = 0; c < 8; ++c) {
      const float Lv = (c < 4) ? va[c] : vb[c - 4];
      const float s2 = (c < 4) ? sa[c] : sb[c - 4];
      const float sc = s1v + s2;
      const float scl = sc >= 0.f ? sc : SLOPE * sc;
      const float ex = (Lv != 0.f) ? __expf(scl) : 0.f;
      dp += ex;
      const unsigned short hh = f2bf(ex);
      ph.u[c] = hh;
      pl.u[c] = f2bf(ex - bf2f(hh));
    }
    *(bf8v*)(ahb[0] + soff) = ph.v;
    *(bf8v*)(alb[0] + soff) = pl.v;
  }

  for (int m = 0; m < 8; ++m) {
    const int t1 = 2 * m + 1;
    f4_t na = *(const f4_t*)(lrow + t1 * 128);
    f4_t nb = *(const f4_t*)(lrow + t1 * 128 + 4);
    f4_t nsa = *(const f4_t*)(s2r + t1 * 128);
    f4_t nsb = *(const f4_t*)(s2r + t1 * 128 + 4);
    #pragma unroll
    for (int si = 0; si < 4; ++si) {
      bhB[si] = *(const bf8v*)(bh_w + ((size_t)t1 * 8 + si) * 2048);
      blB[si] = *(const bf8v*)(bl_w + ((size_t)t1 * 8 + si) * 2048);
    }
    __syncthreads();
    #pragma unroll
    for (int si = 0; si < 4; ++si) {
      const int s = par * 4 + si;
      const int ra16 = (s * 64 + (lane ^ s)) * 16;
      const bf8v ah = *(const bf8v*)(ahb[0] + ra16);
      const bf8v al = *(const bf8v*)(alb[0] + ra16);
      acc = __builtin_amdgcn_mfma_f32_32x32x16_bf16(ah, bhA[si], acc, 0, 0, 0);
      acc = __builtin_amdgcn_mfma_f32_32x32x16_bf16(al, bhA[si], acc, 0, 0, 0);
      acc = __builtin_amdgcn_mfma_f32_32x32x16_bf16(ah, blA[si], acc, 0, 0, 0);
    }
    {
      BFU ph, pl;
      #pragma unroll
      for (int c = 0; c < 8; ++c) {
        const float Lv = (c < 4) ? na[c] : nb[c - 4];
        const float s2 = (c < 4) ? nsa[c] : nsb[c - 4];
        const float sc = s1v + s2;
        const float scl = sc >= 0.f ? sc : SLOPE * sc;
        const float ex = (Lv != 0.f) ? __expf(scl) : 0.f;
        dp += ex;
        const unsigned short hh = f2bf(ex);
        ph.u[c] = hh;
        pl.u[c] = f2bf(ex - bf2f(hh));
      }
      *(bf8v*)(ahb[1] + soff) = ph.v;
      *(bf8v*)(alb[1] + soff) = pl.v;
    }
    if (m < 7) {
      va = *(const f4_t*)(lrow + (t1 + 1) * 128);
      vb = *(const f4_t*)(lrow + (t1 + 1) * 128 + 4);
      sa = *(const f4_t*)(s2r + (t1 + 1) * 128);
      sb = *(const f4_t*)(s2r + (t1 + 1) * 128 + 4);
      #pragma unroll
      for (int si = 0; si < 4; ++si) {
        bhA[si] = *(const bf8v*)(bh_w + ((size_t)(t1 + 1) * 8 + si) * 2048);
        blA[si] = *(const bf8v*)(bl_w + ((size_t)(t1 + 1) * 8 + si) * 2048);
      }
    }
    __syncthreads();
    #pragma unroll
    for (int si = 0; si < 4; ++si) {
      const int s = par * 4 + si;
      const int ra16 = (s * 64 + (lane ^ s)) * 16;
      const bf8v ah = *(const bf8v*)(ahb[1] + ra16);
      const bf8v al = *(const bf8v*)(alb[1] + ra16);
      acc = __builtin_amdgcn_mfma_f32_32x32x16_bf16(ah, bhB[si], acc, 0, 0, 0);
      acc = __builtin_amdgcn_mfma_f32_32x32x16_bf16(al, bhB[si], acc, 0, 0, 0);
      acc = __builtin_amdgcn_mfma_f32_32x32x16_bf16(ah, blB[si], acc, 0, 0, 0);
    }
    if (m < 7) {
      BFU ph, pl;
      #pragma unroll
      for (int c = 0; c < 8; ++c) {
        const float Lv = (c < 4) ? va[c] : vb[c - 4];
        const float s2 = (c < 4) ? sa[c] : sb[c - 4];
        const float sc = s1v + s2;
        const float scl = sc >= 0.f ? sc : SLOPE * sc;
        const float ex = (Lv != 0.f) ? __expf(scl) : 0.f;
        dp += ex;
        const unsigned short hh = f2bf(ex);
        ph.u[c] = hh;
        pl.u[c] = f2bf(ex - bf2f(hh));
      }
      *(bf8v*)(ahb[0] + soff) = ph.v;
      *(bf8v*)(alb[0] + soff) = pl.v;
    }
  }

  dend[srow][t & 15] = dp;
  float* red = (float*)&ahb[0][0];
  __syncthreads();
  if (t < 32) {   // per-row denominator for this (kz,br) K-half
    float d = 0.f;
    #pragma unroll
    for (int i = 0; i < 16; ++i) d += dend[t][i];
    dout[r0 + t] = d;
  }
  const int la = lane & 31;
  if (par == 1) {
    #pragma unroll
    for (int reg = 0; reg < 16; ++reg) {
      const int row = (reg & 3) + 8*(reg >> 2) + 4*(lane >> 5);
      red[n*1024 + row*32 + la] = acc[reg];
    }
  }
  __syncthreads();
  if (par == 0) {
    #pragma unroll
    for (int reg = 0; reg < 16; ++reg) {
      const int row = (reg & 3) + 8*(reg >> 2) + 4*(lane >> 5);
      out[(size_t)(r0 + row) * 128 + n*32 + la] = acc[reg] + red[n*1024 + row*32 + la];
    }
  }
}

// ---------------------------------------------------------------------------
// Dense P @ xWh via MFMA (round-6 form, best measured): BM=32, grid (128,8),
// fragment-ordered B, nt A-loads with one-step prefetch.
__global__ __launch_bounds__(256) void k_pgemm(
    const float* __restrict__ P, const unsigned short* __restrict__ xth,
    const unsigned short* __restrict__ xtl, float* __restrict__ zpart) {
  const int t = threadIdx.x;
  const int w = t >> 6, lane = t & 63;
  const int la = lane & 31;
  const int koff = (lane >> 5) * 8;
  const int r0 = blockIdx.x * 32;
  const int kz = blockIdx.y;
  const int kb = kz * 512 + w * 128;

  f32x16 acc[4];
  #pragma unroll
  for (int n = 0; n < 4; ++n)
    #pragma unroll
    for (int e = 0; e < 16; ++e) acc[n][e] = 0.f;

  const float* __restrict__ arow = P + (size_t)(r0 + la) * NN + kb + koff;
  const unsigned short* __restrict__ bh_base = xth + (size_t)kb * 128 + lane * 8;
  const unsigned short* __restrict__ bl_base = xtl + (size_t)kb * 128 + lane * 8;

  f4_t a0 = __builtin_nontemporal_load((const f4_t*)arow);
  f4_t a1 = __builtin_nontemporal_load((const f4_t*)(arow + 4));
  for (int s = 0; s < 8; ++s) {
    f4_t na0 = a0, na1 = a1;
    if (s < 7) {
      na0 = __builtin_nontemporal_load((const f4_t*)(arow + (s + 1) * 16));
      na1 = __builtin_nontemporal_load((const f4_t*)(arow + (s + 1) * 16 + 4));
    }
    BFU ah, al;
    #pragma unroll
    for (int i = 0; i < 8; ++i) {
      const float f = (i < 4) ? a0[i] : a1[i - 4];
      const unsigned short h = f2bf(f);
      ah.u[i] = h;
      al.u[i] = f2bf(f - bf2f(h));
    }
    const unsigned short* __restrict__ bh_s = bh_base + s * 2048;
    const unsigned short* __restrict__ bl_s = bl_base + s * 2048;
    #pragma unroll
    for (int n = 0; n < 4; ++n) {
      const bf8v bh = *(const bf8v*)(bh_s + n * 512);
      const bf8v bl = *(const bf8v*)(bl_s + n * 512);
      acc[n] = __builtin_amdgcn_mfma_f32_32x32x16_bf16(ah.v, bh, acc[n], 0, 0, 0);
      acc[n] = __builtin_amdgcn_mfma_f32_32x32x16_bf16(al.v, bh, acc[n], 0, 0, 0);
      acc[n] = __builtin_amdgcn_mfma_f32_32x32x16_bf16(ah.v, bl, acc[n], 0, 0, 0);
    }
    a0 = na0; a1 = na1;
  }

  __shared__ float red[2][32][128];
  if (w < 2) {
    #pragma unroll
    for (int n = 0; n < 4; ++n)
      #pragma unroll
      for (int reg = 0; reg < 16; ++reg) {
        const int row = (reg & 3) + 8*(reg >> 2) + 4*(lane >> 5);
        red[w][row][32*n + la] = acc[n][reg];
      }
  }
  __syncthreads();
  if (w >= 2) {
    #pragma unroll
    for (int n = 0; n < 4; ++n)
      #pragma unroll
      for (int reg = 0; reg < 16; ++reg) {
        const int row = (reg & 3) + 8*(reg >> 2) + 4*(lane >> 5);
        red[w - 2][row][32*n + la] += acc[n][reg];
      }
  }
  __syncthreads();
  float* __restrict__ zp = zpart + (size_t)kz * NN * 128;
  #pragma unroll
  for (int i = 0; i < 8; ++i) {
    const int row = w * 8 + i;
    zp[(size_t)(r0 + row) * 128 + lane]      = red[0][row][lane]      + red[1][row][lane];
    zp[(size_t)(r0 + row) * 128 + 64 + lane] = red[0][row][64 + lane] + red[1][row][64 + lane];
  }
}

// ---------------------------------------------------------------------------
// z = (Oi0+Oi1)/di + (Os0+Os1)/ds + sum_k zpart[k] + b_total
__global__ __launch_bounds__(256) void k_combine(const float* __restrict__ ws,
                                                 const float* __restrict__ denp,
                                                 float* __restrict__ z) {
  const int i = blockIdx.x * 256 + threadIdx.x;
  const int col = i & 127;
  const int row = i >> 7;
  const float di = denp[row] + denp[2*NN + row];
  const float ds = denp[NN + row] + denp[3*NN + row];
  const float oi = ws[OI_OFF + i] + ws[HXI_OFF + i];
  const float os = ws[OS_OFF + i] + ws[HXS_OFF + i];
  float acc = ws[BT_OFF + col] + oi / di + os / ds;
  #pragma unroll
  for (int kz = 0; kz < 8; ++kz) acc += ws[ZP_OFF + kz*NN*128 + i];
  z[i] = acc;
}

// ---------------------------------------------------------------------------
extern "C" void kernel_launch(void* const* d_in, const int* in_sizes, int n_in,
                              void* d_out, int out_size, void* d_ws, size_t ws_size,
                              hipStream_t stream) {
  const float* x       = (const float*)d_in[0];
  const float* Lu      = (const float*)d_in[1];
  const float* Ld      = (const float*)d_in[2];
  const float* P       = (const float*)d_in[3];
  const float* Wi_w    = (const float*)d_in[4];
  const float* Wi_b    = (const float*)d_in[5];
  const float* Ws_w    = (const float*)d_in[6];
  const float* Ws_b    = (const float*)d_in[7];
  const float* Wh_w    = (const float*)d_in[8];
  const float* Wh_b    = (const float*)d_in[9];
  const float* att_irr = (const float*)d_in[10];
  const float* att_sol = (const float*)d_in[11];
  float* z  = (float*)d_out;
  float* ws = (float*)d_ws;
  float*          zpart = ws + ZP_OFF;
  unsigned short* xth   = (unsigned short*)(ws + XWH_OFF);
  unsigned short* xtl   = xth + (size_t)128 * NN;
  unsigned short* uih   = (unsigned short*)(ws + UI_OFF);
  unsigned short* uil   = uih + (size_t)128 * NN;
  unsigned short* ush   = (unsigned short*)(ws + US_OFF);
  unsigned short* usl   = ush + (size_t)128 * NN;
  unsigned short* xfh   = (unsigned short*)((char*)d_ws + XF_BYTE_OFF);
  unsigned short* xfl   = xfh + (size_t)128 * NN;
  float*          hx2   = (float*)((char*)d_ws + HX2_BYTE_OFF);
  float*          denp  = (float*)((char*)d_ws + DEN_BYTE_OFF);

  k_prep<<<1, 128, 0, stream>>>(Wi_w, Wi_b, Ws_w, Ws_b, Wh_b, att_irr, att_sol, ws);
  k_pre2<<<1152, 256, 0, stream>>>(x, Wh_w, ws, xth, xtl, xfh, xfl);
  k_hxmm<<<512, 512, 0, stream>>>(Ld, Lu, xfh, xfl, ws, hx2);
  {
    dim3 g(128, 2);
    k_ugemm<<<g, 256, 0, stream>>>(x, Wi_w, Ws_w, ws, hx2, uih, uil, ush, usl);
  }
  k_attnmm<<<512, 512, 0, stream>>>(Ld, Lu, ws, uih, uil, ush, usl, denp);
  {
    dim3 g(128, 8);
    k_pgemm<<<g, 256, 0, stream>>>(P, xth, xtl, zpart);
  }
  k_combine<<<NN * 128 / 256, 256, 0, stream>>>(ws, denp, z);
}